// Round 5
// baseline (577.776 us; speedup 1.0000x reference)
//
#include <hip/hip_runtime.h>
#include <hip/hip_bf16.h>

// ExpertBank MoE FFN on gfx950 — round 5.
// cvtX -> setup(count+scan+assign, 1 block) -> tw(W1) -> GEMM1(BK64, gelu->H bf16)
//   -> tw(W2, same buffer) -> GEMM2(BK64, full-K, plain-store scatter).
// No memset, no atomics in GEMM epilogues, 6 dispatches total.
// ws: int[0..7] counts, [16..23] opad, [32..) rowmap(9216),
//     byte 65536: H bf16 [9216][2048] (37.75 MB), Xb bf16 [4096][512] (4.2 MB),
//     WT bf16 [8][2048*512] (16.8 MB; W1T then overwritten by W2T). need=58.85MB
//     (exact same constant proven available in round 4).

typedef __bf16 bf16x8 __attribute__((ext_vector_type(8)));
typedef float f32x4 __attribute__((ext_vector_type(4)));

#define DM 512
#define DF 2048
#define NE 8
#define NTOK 4096
#define NPAIR 8192
#define HCAP 9216

__device__ __forceinline__ unsigned short f2bf(float x) {
    unsigned u = __builtin_bit_cast(unsigned, x);
    return (unsigned short)((u + 0x7fffu + ((u >> 16) & 1u)) >> 16);
}
__device__ __forceinline__ unsigned pack2(float lo, float hi) {
    return (unsigned)f2bf(lo) | ((unsigned)f2bf(hi) << 16);
}
__device__ __forceinline__ float gelu_exact(float x) {
    return 0.5f * x * (1.0f + erff(x * 0.70710678118654752440f));
}

// ---- fused routing: histogram + padded scan + compact assign, one block ----
__global__ void k_setup(const int* __restrict__ sel, int* __restrict__ counts_g,
                        int* __restrict__ opad_g, int* __restrict__ rowmap,
                        float* __restrict__ loads_out) {
    __shared__ int hist[NE], cur[NE], off[NE];
    const int tid = threadIdx.x;
    if (tid < NE) { hist[tid] = 0; cur[tid] = 0; }
    __syncthreads();
#pragma unroll
    for (int i = 0; i < NPAIR / 256; ++i)
        atomicAdd(&hist[sel[i * 256 + tid]], 1);
    __syncthreads();
    if (tid == 0) {
        int s = 0;
        for (int e = 0; e < NE; ++e) {
            off[e] = s;
            s += (hist[e] + 127) & ~127;
            counts_g[e] = hist[e];
            opad_g[e] = off[e];
            loads_out[e] = (float)hist[e] * (1.0f / (float)NTOK);
        }
    }
    __syncthreads();
#pragma unroll
    for (int i = 0; i < NPAIR / 256; ++i) {
        int p = i * 256 + tid;
        int e = sel[p];
        int pos = atomicAdd(&cur[e], 1);
        rowmap[off[e] + pos] = p;
    }
}

// ---- X fp32 -> bf16 ----
__global__ void k_cvtx(const float* __restrict__ X, unsigned short* __restrict__ Xb) {
    int i = (blockIdx.x * 256 + threadIdx.x) * 8;
    float4 a = *(const float4*)(X + i);
    float4 b = *(const float4*)(X + i + 4);
    uint4 u;
    u.x = pack2(a.x, a.y); u.y = pack2(a.z, a.w);
    u.z = pack2(b.x, b.y); u.w = pack2(b.z, b.w);
    *(uint4*)(Xb + i) = u;
}

// ---- W fp32 [E][R][C] -> bf16 transpose [E][C][R], 64x64 LDS tiles ----
__global__ void k_tw(const float* __restrict__ in, unsigned short* __restrict__ out,
                     int R, int C) {
    __shared__ unsigned short T[64][65];
    const int tid = threadIdx.x;
    const int tx = tid & 15, ty = tid >> 4;
    const int r0 = blockIdx.y * 64, c0 = blockIdx.x * 64;
    const float* src = in + ((size_t)blockIdx.z * R + r0) * C + c0;
#pragma unroll
    for (int i = 0; i < 4; ++i) {
        int r = ty + i * 16;
        float4 v = *(const float4*)(src + (size_t)r * C + tx * 4);
        T[tx * 4 + 0][r] = f2bf(v.x); T[tx * 4 + 1][r] = f2bf(v.y);
        T[tx * 4 + 2][r] = f2bf(v.z); T[tx * 4 + 3][r] = f2bf(v.w);
    }
    __syncthreads();
    unsigned short* dst = out + ((size_t)blockIdx.z * C + c0) * R + r0;
#pragma unroll
    for (int i = 0; i < 4; ++i) {
        int c = ty + i * 16;
        ushort4 w;
        w.x = T[c][tx * 4 + 0]; w.y = T[c][tx * 4 + 1];
        w.z = T[c][tx * 4 + 2]; w.w = T[c][tx * 4 + 3];
        *(ushort4*)(dst + (size_t)c * R + tx * 4) = w;
    }
}

// ---------------- GEMM1: H = gelu(Xb[tok] @ W1), 128x128 tile, BK=64, 8 iters -------
__launch_bounds__(256, 3)
__global__ void k_gemm1(const unsigned short* __restrict__ Xb,
                        const unsigned short* __restrict__ W1T,
                        const int* __restrict__ counts, const int* __restrict__ opad,
                        const int* __restrict__ rowmap, unsigned short* __restrict__ H) {
    const int e = blockIdx.z, mt = blockIdx.y, nt = blockIdx.x;
    const int grow = opad[e] + mt * 128;
    int valid = counts[e] - mt * 128;
    if (valid <= 0) return;
    if (valid > 128) valid = 128;

    __shared__ __align__(16) unsigned short As[128 * 72];
    __shared__ __align__(16) unsigned short Bs[128 * 72];
    __shared__ int toks[128];

    const int tid = threadIdx.x;
    if (tid < 128) {
        int i = (tid < valid) ? tid : 0;
        toks[tid] = rowmap[grow + i] >> 1;
    }
    __syncthreads();

    const int wave = tid >> 6, lane = tid & 63;
    const int wm = wave >> 1, wn = wave & 1;
    const int quad = lane >> 4, l15 = lane & 15;

    f32x4 acc[4][4] = {};

    const int row = tid >> 1, half = tid & 1;
    const unsigned short* ap = Xb + (size_t)toks[row] * DM + half * 32;
    const unsigned short* bp = W1T + ((size_t)e * DF + nt * 128 + row) * DM + half * 32;
    const int lo = row * 72 + half * 32;

    uint4 pa[4], pb[4];
#pragma unroll
    for (int j = 0; j < 4; ++j) {
        pa[j] = *(const uint4*)(ap + j * 8);
        pb[j] = *(const uint4*)(bp + j * 8);
    }

    for (int kt = 0; kt < DM / 64; ++kt) {
#pragma unroll
        for (int j = 0; j < 4; ++j) {
            *(uint4*)&As[lo + j * 8] = pa[j];
            *(uint4*)&Bs[lo + j * 8] = pb[j];
        }
        __syncthreads();
        const int kn = (kt < DM / 64 - 1 ? kt + 1 : kt) * 64;
#pragma unroll
        for (int j = 0; j < 4; ++j) {
            pa[j] = *(const uint4*)(ap + kn + j * 8);
            pb[j] = *(const uint4*)(bp + kn + j * 8);
        }
#pragma unroll
        for (int ks = 0; ks < 2; ++ks) {
            bf16x8 a[4], b[4];
#pragma unroll
            for (int fm = 0; fm < 4; ++fm)
                a[fm] = __builtin_bit_cast(bf16x8,
                    *(const uint4*)&As[(wm * 64 + fm * 16 + l15) * 72 + ks * 32 + quad * 8]);
#pragma unroll
            for (int fn = 0; fn < 4; ++fn)
                b[fn] = __builtin_bit_cast(bf16x8,
                    *(const uint4*)&Bs[(wn * 64 + fn * 16 + l15) * 72 + ks * 32 + quad * 8]);
#pragma unroll
            for (int fm = 0; fm < 4; ++fm)
#pragma unroll
                for (int fn = 0; fn < 4; ++fn)
                    acc[fm][fn] = __builtin_amdgcn_mfma_f32_16x16x32_bf16(a[fm], b[fn], acc[fm][fn], 0, 0, 0);
        }
        __syncthreads();
    }

#pragma unroll
    for (int fm = 0; fm < 4; ++fm) {
#pragma unroll
        for (int i = 0; i < 4; ++i) {
            int m_l = wm * 64 + fm * 16 + quad * 4 + i;
            if (m_l < valid) {
                unsigned short* hrow = H + (size_t)(grow + m_l) * DF + nt * 128 + wn * 64;
#pragma unroll
                for (int fn = 0; fn < 4; ++fn)
                    hrow[fn * 16 + l15] = f2bf(gelu_exact(acc[fm][fn][i]));
            }
        }
    }
}

// ---------------- GEMM2: out[pair] = H @ W2, 128x64 tile, BK=64, 32 iters, stores ----
__launch_bounds__(256, 3)
__global__ void k_gemm2(const unsigned short* __restrict__ H,
                        const unsigned short* __restrict__ W2T,
                        const int* __restrict__ counts, const int* __restrict__ opad,
                        const int* __restrict__ rowmap, float* __restrict__ out) {
    const int e = blockIdx.z, mt = blockIdx.y, nt = blockIdx.x;
    const int grow = opad[e] + mt * 128;
    int valid = counts[e] - mt * 128;
    if (valid <= 0) return;
    if (valid > 128) valid = 128;

    __shared__ __align__(16) unsigned short As[128 * 72];
    __shared__ __align__(16) unsigned short Bs[64 * 72];
    __shared__ int pairs[128];

    const int tid = threadIdx.x;
    if (tid < 128) pairs[tid] = (tid < valid) ? rowmap[grow + tid] : 0;
    __syncthreads();

    const int wave = tid >> 6, lane = tid & 63;
    const int wm = wave >> 1, wn = wave & 1;
    const int quad = lane >> 4, l15 = lane & 15;

    f32x4 acc[4][2] = {};

    const int arow = tid >> 1, ahalf = tid & 1;
    const int rr = (arow < valid) ? arow : 0;
    const unsigned short* ap = H + (size_t)(grow + rr) * DF + ahalf * 32;
    const int alo = arow * 72 + ahalf * 32;
    const int brow = tid >> 2, bsub = tid & 3;
    const unsigned short* bp = W2T + ((size_t)e * DM + nt * 64 + brow) * DF + bsub * 16;
    const int blo = brow * 72 + bsub * 16;

    uint4 pa[4], pb[2];
#pragma unroll
    for (int j = 0; j < 4; ++j) pa[j] = *(const uint4*)(ap + j * 8);
#pragma unroll
    for (int j = 0; j < 2; ++j) pb[j] = *(const uint4*)(bp + j * 8);

    for (int kt = 0; kt < DF / 64; ++kt) {
#pragma unroll
        for (int j = 0; j < 4; ++j) *(uint4*)&As[alo + j * 8] = pa[j];
#pragma unroll
        for (int j = 0; j < 2; ++j) *(uint4*)&Bs[blo + j * 8] = pb[j];
        __syncthreads();
        const int kn = (kt < DF / 64 - 1 ? kt + 1 : kt) * 64;
#pragma unroll
        for (int j = 0; j < 4; ++j) pa[j] = *(const uint4*)(ap + kn + j * 8);
#pragma unroll
        for (int j = 0; j < 2; ++j) pb[j] = *(const uint4*)(bp + kn + j * 8);
#pragma unroll
        for (int ks = 0; ks < 2; ++ks) {
            bf16x8 a[4], b[2];
#pragma unroll
            for (int fm = 0; fm < 4; ++fm)
                a[fm] = __builtin_bit_cast(bf16x8,
                    *(const uint4*)&As[(wm * 64 + fm * 16 + l15) * 72 + ks * 32 + quad * 8]);
#pragma unroll
            for (int fn = 0; fn < 2; ++fn)
                b[fn] = __builtin_bit_cast(bf16x8,
                    *(const uint4*)&Bs[(wn * 32 + fn * 16 + l15) * 72 + ks * 32 + quad * 8]);
#pragma unroll
            for (int fm = 0; fm < 4; ++fm)
#pragma unroll
                for (int fn = 0; fn < 2; ++fn)
                    acc[fm][fn] = __builtin_amdgcn_mfma_f32_16x16x32_bf16(a[fm], b[fn], acc[fm][fn], 0, 0, 0);
        }
        __syncthreads();
    }

#pragma unroll
    for (int fm = 0; fm < 4; ++fm) {
#pragma unroll
        for (int i = 0; i < 4; ++i) {
            int m_l = wm * 64 + fm * 16 + quad * 4 + i;
            if (m_l < valid) {
                float* orow = out + (size_t)pairs[m_l] * DM + nt * 64 + wn * 32;
#pragma unroll
                for (int fn = 0; fn < 2; ++fn)
                    orow[fn * 16 + l15] = acc[fm][fn][i];
            }
        }
    }
}

extern "C" void kernel_launch(void* const* d_in, const int* in_sizes, int n_in,
                              void* d_out, int out_size, void* d_ws, size_t ws_size,
                              hipStream_t stream) {
    const float* X = (const float*)d_in[0];
    const int* sel = (const int*)d_in[1];
    const float* W1 = (const float*)d_in[3];
    const float* W2 = (const float*)d_in[4];
    float* out = (float*)d_out;
    float* loads_out = out + (size_t)NPAIR * DM;

    int* counts = (int*)d_ws;
    int* opad = counts + 16;
    int* rowmap = counts + 32;
    const size_t hbytes = (size_t)HCAP * DF * 2;
    const size_t xbytes = (size_t)NTOK * DM * 2;
    unsigned short* H = (unsigned short*)((char*)d_ws + 65536);
    unsigned short* Xb = (unsigned short*)((char*)d_ws + 65536 + hbytes);
    unsigned short* WT = (unsigned short*)((char*)d_ws + 65536 + hbytes + xbytes);

    hipLaunchKernelGGL(k_cvtx, dim3(NTOK * DM / 2048), dim3(256), 0, stream, X, Xb);
    hipLaunchKernelGGL(k_setup, dim3(1), dim3(256), 0, stream, sel, counts, opad, rowmap, loads_out);
    hipLaunchKernelGGL(k_tw, dim3(DF / 64, DM / 64, NE), dim3(256), 0, stream, W1, WT, DM, DF);
    hipLaunchKernelGGL(k_gemm1, dim3(DF / 128, NPAIR / 128, NE), dim3(256), 0, stream,
                       Xb, WT, counts, opad, rowmap, H);
    hipLaunchKernelGGL(k_tw, dim3(DM / 64, DF / 64, NE), dim3(256), 0, stream, W2, WT, DF, DM);
    hipLaunchKernelGGL(k_gemm2, dim3(DM / 64, NPAIR / 128, NE), dim3(256), 0, stream,
                       H, WT, counts, opad, rowmap, out);
}

// Round 6
// 260.877 us; speedup vs baseline: 2.2147x; 2.2147x over previous
//
#include <hip/hip_runtime.h>
#include <hip/hip_bf16.h>

// ExpertBank MoE FFN on gfx950 — round 6.
// 4 dispatches: k_prep(cvtX || tw(W1) || zero(out) || routing)
//   -> GEMM1(r4-proven, BK32 128x128, gelu->H bf16)
//   -> tw(W2, same WT buffer)
//   -> GEMM2(r4-proven split-K x4 + atomics, + XCD swizzle for H reuse).
// ws: int[0..7] counts, [16..23] opad, [32..) rowmap(9216),
//     byte 65536: H bf16 [9216][2048] (37.75 MB), Xb bf16 [4096][512] (4.2 MB),
//     WT bf16 [8][2048*512] (16.8 MB; W1T then overwritten by W2T).
//     need = 58.85 MB — proven available on HW in round 4.

typedef __bf16 bf16x8 __attribute__((ext_vector_type(8)));
typedef float f32x4 __attribute__((ext_vector_type(4)));

#define DM 512
#define DF 2048
#define NE 8
#define NTOK 4096
#define NPAIR 8192
#define HCAP 9216

__device__ __forceinline__ unsigned short f2bf(float x) {
    unsigned u = __builtin_bit_cast(unsigned, x);
    return (unsigned short)((u + 0x7fffu + ((u >> 16) & 1u)) >> 16);
}
__device__ __forceinline__ unsigned pack2(float lo, float hi) {
    return (unsigned)f2bf(lo) | ((unsigned)f2bf(hi) << 16);
}
__device__ __forceinline__ float gelu_exact(float x) {
    return 0.5f * x * (1.0f + erff(x * 0.70710678118654752440f));
}

// ---- mega-prep: blocks [0,1024) cvtX, [1024,3072) transpose W1, [3072,5120) zero out,
//                 block 5120 fused routing (hist+scan+assign). All parts independent. ----
__global__ void k_prep(const float* __restrict__ X, unsigned short* __restrict__ Xb,
                       const float* __restrict__ W1, unsigned short* __restrict__ W1T,
                       float* __restrict__ outz,
                       const int* __restrict__ sel, int* __restrict__ counts_g,
                       int* __restrict__ opad_g, int* __restrict__ rowmap,
                       float* __restrict__ loads_out) {
    __shared__ unsigned short T[64][65];
    __shared__ int hist[NE], cur[NE], off[NE];
    const int b = blockIdx.x, tid = threadIdx.x;

    if (b < 1024) {  // ---- X fp32 -> bf16 ----
        int i = (b * 256 + tid) * 8;
        float4 a = *(const float4*)(X + i);
        float4 c = *(const float4*)(X + i + 4);
        uint4 u;
        u.x = pack2(a.x, a.y); u.y = pack2(a.z, a.w);
        u.z = pack2(c.x, c.y); u.w = pack2(c.z, c.w);
        *(uint4*)(Xb + i) = u;
    } else if (b < 3072) {  // ---- W1 [E][DM][DF] -> bf16 W1T [E][DF][DM] ----
        const int t = b - 1024;
        const int bx = t & 31, by = (t >> 5) & 7, bz = t >> 8;  // x: DF/64, y: DM/64, z: E
        const int tx = tid & 15, ty = tid >> 4;
        const int r0 = by * 64, c0 = bx * 64;
        const float* src = W1 + ((size_t)bz * DM + r0) * DF + c0;
#pragma unroll
        for (int i = 0; i < 4; ++i) {
            int r = ty + i * 16;
            float4 v = *(const float4*)(src + (size_t)r * DF + tx * 4);
            T[tx * 4 + 0][r] = f2bf(v.x); T[tx * 4 + 1][r] = f2bf(v.y);
            T[tx * 4 + 2][r] = f2bf(v.z); T[tx * 4 + 3][r] = f2bf(v.w);
        }
        __syncthreads();
        unsigned short* dst = W1T + ((size_t)bz * DF + c0) * DM + r0;
#pragma unroll
        for (int i = 0; i < 4; ++i) {
            int c = ty + i * 16;
            ushort4 w;
            w.x = T[c][tx * 4 + 0]; w.y = T[c][tx * 4 + 1];
            w.z = T[c][tx * 4 + 2]; w.w = T[c][tx * 4 + 3];
            *(ushort4*)(dst + (size_t)c * DM + tx * 4) = w;
        }
    } else if (b < 5120) {  // ---- zero expert_outputs (needed by gemm2 atomics) ----
        size_t i = ((size_t)(b - 3072) * 256 + tid) * 8;
        float4 z = make_float4(0.f, 0.f, 0.f, 0.f);
        *(float4*)(outz + i) = z;
        *(float4*)(outz + i + 4) = z;
    } else {  // ---- routing: histogram + padded scan + compact assign ----
        if (tid < NE) { hist[tid] = 0; cur[tid] = 0; }
        __syncthreads();
#pragma unroll
        for (int i = 0; i < NPAIR / 256; ++i)
            atomicAdd(&hist[sel[i * 256 + tid]], 1);
        __syncthreads();
        if (tid == 0) {
            int s = 0;
            for (int e = 0; e < NE; ++e) {
                off[e] = s;
                s += (hist[e] + 127) & ~127;
                counts_g[e] = hist[e];
                opad_g[e] = off[e];
                loads_out[e] = (float)hist[e] * (1.0f / (float)NTOK);
            }
        }
        __syncthreads();
#pragma unroll
        for (int i = 0; i < NPAIR / 256; ++i) {
            int p = i * 256 + tid;
            int e = sel[p];
            int pos = atomicAdd(&cur[e], 1);
            rowmap[off[e] + pos] = p;
        }
    }
}

// ---- W2 [E][DF][DM] -> bf16 W2T [E][DM][DF] (runs after gemm1; reuses WT buffer) ----
__global__ void k_tw2(const float* __restrict__ in, unsigned short* __restrict__ out) {
    __shared__ unsigned short T[64][65];
    const int tid = threadIdx.x;
    const int tx = tid & 15, ty = tid >> 4;
    const int r0 = blockIdx.y * 64, c0 = blockIdx.x * 64;  // R=DF rows, C=DM cols
    const float* src = in + ((size_t)blockIdx.z * DF + r0) * DM + c0;
#pragma unroll
    for (int i = 0; i < 4; ++i) {
        int r = ty + i * 16;
        float4 v = *(const float4*)(src + (size_t)r * DM + tx * 4);
        T[tx * 4 + 0][r] = f2bf(v.x); T[tx * 4 + 1][r] = f2bf(v.y);
        T[tx * 4 + 2][r] = f2bf(v.z); T[tx * 4 + 3][r] = f2bf(v.w);
    }
    __syncthreads();
    unsigned short* dst = out + ((size_t)blockIdx.z * DM + c0) * DF + r0;
#pragma unroll
    for (int i = 0; i < 4; ++i) {
        int c = ty + i * 16;
        ushort4 w;
        w.x = T[c][tx * 4 + 0]; w.y = T[c][tx * 4 + 1];
        w.z = T[c][tx * 4 + 2]; w.w = T[c][tx * 4 + 3];
        *(ushort4*)(dst + (size_t)c * DF + tx * 4) = w;
    }
}

// ---------------- GEMM1 (round-4 proven): H = gelu(Xb[tok] @ W1), 128x128, BK=32 -----
__launch_bounds__(256, 3)
__global__ void k_gemm1b(const unsigned short* __restrict__ Xb,
                         const unsigned short* __restrict__ W1T,
                         const int* __restrict__ counts, const int* __restrict__ opad,
                         const int* __restrict__ rowmap, unsigned short* __restrict__ H) {
    const int e = blockIdx.z, mt = blockIdx.y, nt = blockIdx.x;
    const int grow = opad[e] + mt * 128;
    int valid = counts[e] - mt * 128;
    if (valid <= 0) return;
    if (valid > 128) valid = 128;

    __shared__ __align__(16) unsigned short As[128 * 40];
    __shared__ __align__(16) unsigned short Bs[128 * 40];
    __shared__ int toks[128];

    const int tid = threadIdx.x;
    if (tid < 128) {
        int i = (tid < valid) ? tid : 0;
        toks[tid] = rowmap[grow + i] >> 1;
    }
    __syncthreads();

    const int wave = tid >> 6, lane = tid & 63;
    const int wm = wave >> 1, wn = wave & 1;
    const int quad = lane >> 4, l15 = lane & 15;

    f32x4 acc[4][4] = {};

    const int row = tid >> 1, half = tid & 1;
    const unsigned short* ap = Xb + (size_t)toks[row] * DM + half * 16;
    const unsigned short* bp = W1T + ((size_t)e * DF + nt * 128 + row) * DM + half * 16;
    const int lo = row * 40 + half * 16;

    uint4 pa0 = *(const uint4*)ap, pa1 = *(const uint4*)(ap + 8);
    uint4 pb0 = *(const uint4*)bp, pb1 = *(const uint4*)(bp + 8);

    for (int kt = 0; kt < DM / 32; ++kt) {
        *(uint4*)&As[lo] = pa0; *(uint4*)&As[lo + 8] = pa1;
        *(uint4*)&Bs[lo] = pb0; *(uint4*)&Bs[lo + 8] = pb1;
        __syncthreads();
        const int kn = (kt < DM / 32 - 1) ? (kt + 1) * 32 : kt * 32;
        uint4 na0 = *(const uint4*)(ap + kn), na1 = *(const uint4*)(ap + kn + 8);
        uint4 nb0 = *(const uint4*)(bp + kn), nb1 = *(const uint4*)(bp + kn + 8);

        bf16x8 a[4], b[4];
#pragma unroll
        for (int fm = 0; fm < 4; ++fm)
            a[fm] = __builtin_bit_cast(bf16x8, *(const uint4*)&As[(wm * 64 + fm * 16 + l15) * 40 + quad * 8]);
#pragma unroll
        for (int fn = 0; fn < 4; ++fn)
            b[fn] = __builtin_bit_cast(bf16x8, *(const uint4*)&Bs[(wn * 64 + fn * 16 + l15) * 40 + quad * 8]);
#pragma unroll
        for (int fm = 0; fm < 4; ++fm)
#pragma unroll
            for (int fn = 0; fn < 4; ++fn)
                acc[fm][fn] = __builtin_amdgcn_mfma_f32_16x16x32_bf16(a[fm], b[fn], acc[fm][fn], 0, 0, 0);
        __syncthreads();
        pa0 = na0; pa1 = na1; pb0 = nb0; pb1 = nb1;
    }

#pragma unroll
    for (int fm = 0; fm < 4; ++fm) {
#pragma unroll
        for (int i = 0; i < 4; ++i) {
            int m_l = wm * 64 + fm * 16 + quad * 4 + i;
            if (m_l < valid) {
                unsigned short* hrow = H + (size_t)(grow + m_l) * DF + nt * 128 + wn * 64;
#pragma unroll
                for (int fn = 0; fn < 4; ++fn)
                    hrow[fn * 16 + l15] = f2bf(gelu_exact(acc[fm][fn][i]));
            }
        }
    }
}

// ---------------- GEMM2 (round-4 proven + XCD swizzle): out += H @ W2, split-K x4 ----
// Swizzle: the 4 nt-siblings sharing one 128-row H slice get linear ids == (mod 8)
// within a 32-block window -> same XCD -> slice fetched ~once into that XCD's L2.
__launch_bounds__(256, 3)
__global__ void k_gemm2b(const unsigned short* __restrict__ H,
                         const unsigned short* __restrict__ W2T,
                         const int* __restrict__ counts, const int* __restrict__ opad,
                         const int* __restrict__ rowmap, float* __restrict__ out) {
    const int L = blockIdx.x + 16 * blockIdx.y + 1152 * blockIdx.z;  // grid (16,72,8)
    const int nt = (L >> 3) & 3;
    const int g = ((L >> 5) << 3) | (L & 7);   // 0..2303
    const int ks = g & 3;
    const int emt = g >> 2;                    // 0..575
    const int e = emt / 72;
    const int mt = emt - e * 72;

    const int grow = opad[e] + mt * 128;
    int valid = counts[e] - mt * 128;
    if (valid <= 0) return;
    if (valid > 128) valid = 128;

    __shared__ __align__(16) unsigned short As[128 * 40];
    __shared__ __align__(16) unsigned short Bs[128 * 40];
    __shared__ int pairs[128];

    const int tid = threadIdx.x;
    if (tid < 128) pairs[tid] = (tid < valid) ? rowmap[grow + tid] : 0;
    __syncthreads();

    const int wave = tid >> 6, lane = tid & 63;
    const int wm = wave >> 1, wn = wave & 1;
    const int quad = lane >> 4, l15 = lane & 15;

    f32x4 acc[4][4] = {};

    const int row = tid >> 1, half = tid & 1;
    const int rr = (row < valid) ? row : 0;
    const unsigned short* ap = H + (size_t)(grow + rr) * DF + ks * 512 + half * 16;
    const unsigned short* bp = W2T + ((size_t)e * DM + nt * 128 + row) * DF + ks * 512 + half * 16;
    const int lo = row * 40 + half * 16;

    uint4 pa0 = *(const uint4*)ap, pa1 = *(const uint4*)(ap + 8);
    uint4 pb0 = *(const uint4*)bp, pb1 = *(const uint4*)(bp + 8);

    for (int kt = 0; kt < 16; ++kt) {
        *(uint4*)&As[lo] = pa0; *(uint4*)&As[lo + 8] = pa1;
        *(uint4*)&Bs[lo] = pb0; *(uint4*)&Bs[lo + 8] = pb1;
        __syncthreads();
        const int kn = (kt < 15) ? (kt + 1) * 32 : kt * 32;
        uint4 na0 = *(const uint4*)(ap + kn), na1 = *(const uint4*)(ap + kn + 8);
        uint4 nb0 = *(const uint4*)(bp + kn), nb1 = *(const uint4*)(bp + kn + 8);

        bf16x8 a[4], b[4];
#pragma unroll
        for (int fm = 0; fm < 4; ++fm)
            a[fm] = __builtin_bit_cast(bf16x8, *(const uint4*)&As[(wm * 64 + fm * 16 + l15) * 40 + quad * 8]);
#pragma unroll
        for (int fn = 0; fn < 4; ++fn)
            b[fn] = __builtin_bit_cast(bf16x8, *(const uint4*)&Bs[(wn * 64 + fn * 16 + l15) * 40 + quad * 8]);
#pragma unroll
        for (int fm = 0; fm < 4; ++fm)
#pragma unroll
            for (int fn = 0; fn < 4; ++fn)
                acc[fm][fn] = __builtin_amdgcn_mfma_f32_16x16x32_bf16(a[fm], b[fn], acc[fm][fn], 0, 0, 0);
        __syncthreads();
        pa0 = na0; pa1 = na1; pb0 = nb0; pb1 = nb1;
    }

#pragma unroll
    for (int fm = 0; fm < 4; ++fm) {
#pragma unroll
        for (int i = 0; i < 4; ++i) {
            int m_l = wm * 64 + fm * 16 + quad * 4 + i;
            if (m_l < valid) {
                float* orow = out + (size_t)pairs[m_l] * DM + nt * 128 + wn * 64;
#pragma unroll
                for (int fn = 0; fn < 4; ++fn)
                    atomicAdd(&orow[fn * 16 + l15], acc[fm][fn][i]);
            }
        }
    }
}

extern "C" void kernel_launch(void* const* d_in, const int* in_sizes, int n_in,
                              void* d_out, int out_size, void* d_ws, size_t ws_size,
                              hipStream_t stream) {
    const float* X = (const float*)d_in[0];
    const int* sel = (const int*)d_in[1];
    const float* W1 = (const float*)d_in[3];
    const float* W2 = (const float*)d_in[4];
    float* out = (float*)d_out;
    float* loads_out = out + (size_t)NPAIR * DM;

    int* counts = (int*)d_ws;
    int* opad = counts + 16;
    int* rowmap = counts + 32;
    const size_t hbytes = (size_t)HCAP * DF * 2;
    const size_t xbytes = (size_t)NTOK * DM * 2;
    unsigned short* H = (unsigned short*)((char*)d_ws + 65536);
    unsigned short* Xb = (unsigned short*)((char*)d_ws + 65536 + hbytes);
    unsigned short* WT = (unsigned short*)((char*)d_ws + 65536 + hbytes + xbytes);

    hipLaunchKernelGGL(k_prep, dim3(5121), dim3(256), 0, stream,
                       X, Xb, W1, WT, out, sel, counts, opad, rowmap, loads_out);
    hipLaunchKernelGGL(k_gemm1b, dim3(DF / 128, NPAIR / 128, NE), dim3(256), 0, stream,
                       Xb, WT, counts, opad, rowmap, H);
    hipLaunchKernelGGL(k_tw2, dim3(DM / 64, DF / 64, NE), dim3(256), 0, stream, W2, WT);
    hipLaunchKernelGGL(k_gemm2b, dim3(16, NPAIR / 128, NE), dim3(256), 0, stream,
                       H, WT, counts, opad, rowmap, out);
}

// Round 8
// 253.805 us; speedup vs baseline: 2.2765x; 1.0279x over previous
//
#include <hip/hip_runtime.h>
#include <hip/hip_bf16.h>

// ExpertBank MoE FFN on gfx950 — round 8 (= round 6 minus atomics).
// 4 dispatches: k_prep(cvtX || tw(W1) || routing) -> GEMM1(r6-proven) -> tw(W2)
//   -> GEMM2n (64x64 tiles, full-K, plain stores, no atomics, no out zeroing).
// All ws regions are written by this call before being read (r7 lesson).
// ws: int[0..7] counts, [16..23] opad, [32..) rowmap(9216),
//     byte 65536: H bf16 [9216][2048] (37.75 MB), Xb bf16 (4.2 MB),
//     WT bf16 (16.8 MB; W1T then overwritten by W2T). need = 58.85 MB (proven r4/r6).

typedef __bf16 bf16x8 __attribute__((ext_vector_type(8)));
typedef float f32x4 __attribute__((ext_vector_type(4)));

#define DM 512
#define DF 2048
#define NE 8
#define NTOK 4096
#define NPAIR 8192
#define HCAP 9216

__device__ __forceinline__ unsigned short f2bf(float x) {
    unsigned u = __builtin_bit_cast(unsigned, x);
    return (unsigned short)((u + 0x7fffu + ((u >> 16) & 1u)) >> 16);
}
__device__ __forceinline__ unsigned pack2(float lo, float hi) {
    return (unsigned)f2bf(lo) | ((unsigned)f2bf(hi) << 16);
}
__device__ __forceinline__ float gelu_exact(float x) {
    return 0.5f * x * (1.0f + erff(x * 0.70710678118654752440f));
}

// ---- mega-prep: blocks [0,1024) cvtX, [1024,3072) transpose W1, 3072 routing ----
__global__ void k_prep(const float* __restrict__ X, unsigned short* __restrict__ Xb,
                       const float* __restrict__ W1, unsigned short* __restrict__ W1T,
                       const int* __restrict__ sel, int* __restrict__ counts_g,
                       int* __restrict__ opad_g, int* __restrict__ rowmap,
                       float* __restrict__ loads_out) {
    __shared__ unsigned short T[64][65];
    __shared__ int hist[NE], cur[NE], off[NE];
    const int b = blockIdx.x, tid = threadIdx.x;

    if (b < 1024) {  // X fp32 -> bf16
        int i = (b * 256 + tid) * 8;
        float4 a = *(const float4*)(X + i);
        float4 c = *(const float4*)(X + i + 4);
        uint4 u;
        u.x = pack2(a.x, a.y); u.y = pack2(a.z, a.w);
        u.z = pack2(c.x, c.y); u.w = pack2(c.z, c.w);
        *(uint4*)(Xb + i) = u;
    } else if (b < 3072) {  // W1 [E][DM][DF] -> bf16 W1T [E][DF][DM]
        const int t = b - 1024;
        const int bx = t & 31, by = (t >> 5) & 7, bz = t >> 8;
        const int tx = tid & 15, ty = tid >> 4;
        const int r0 = by * 64, c0 = bx * 64;
        const float* src = W1 + ((size_t)bz * DM + r0) * DF + c0;
#pragma unroll
        for (int i = 0; i < 4; ++i) {
            int r = ty + i * 16;
            float4 v = *(const float4*)(src + (size_t)r * DF + tx * 4);
            T[tx * 4 + 0][r] = f2bf(v.x); T[tx * 4 + 1][r] = f2bf(v.y);
            T[tx * 4 + 2][r] = f2bf(v.z); T[tx * 4 + 3][r] = f2bf(v.w);
        }
        __syncthreads();
        unsigned short* dst = W1T + ((size_t)bz * DF + c0) * DM + r0;
#pragma unroll
        for (int i = 0; i < 4; ++i) {
            int c = ty + i * 16;
            ushort4 w;
            w.x = T[c][tx * 4 + 0]; w.y = T[c][tx * 4 + 1];
            w.z = T[c][tx * 4 + 2]; w.w = T[c][tx * 4 + 3];
            *(ushort4*)(dst + (size_t)c * DM + tx * 4) = w;
        }
    } else {  // routing: histogram + padded scan + compact assign
        if (tid < NE) { hist[tid] = 0; cur[tid] = 0; }
        __syncthreads();
#pragma unroll
        for (int i = 0; i < NPAIR / 256; ++i)
            atomicAdd(&hist[sel[i * 256 + tid]], 1);
        __syncthreads();
        if (tid == 0) {
            int s = 0;
            for (int e = 0; e < NE; ++e) {
                off[e] = s;
                s += (hist[e] + 127) & ~127;
                counts_g[e] = hist[e];
                opad_g[e] = off[e];
                loads_out[e] = (float)hist[e] * (1.0f / (float)NTOK);
            }
        }
        __syncthreads();
#pragma unroll
        for (int i = 0; i < NPAIR / 256; ++i) {
            int p = i * 256 + tid;
            int e = sel[p];
            int pos = atomicAdd(&cur[e], 1);
            rowmap[off[e] + pos] = p;
        }
    }
}

// ---- W2 [E][DF][DM] -> bf16 W2T [E][DM][DF] ----
__global__ void k_tw2(const float* __restrict__ in, unsigned short* __restrict__ out) {
    __shared__ unsigned short T[64][65];
    const int tid = threadIdx.x;
    const int tx = tid & 15, ty = tid >> 4;
    const int r0 = blockIdx.y * 64, c0 = blockIdx.x * 64;
    const float* src = in + ((size_t)blockIdx.z * DF + r0) * DM + c0;
#pragma unroll
    for (int i = 0; i < 4; ++i) {
        int r = ty + i * 16;
        float4 v = *(const float4*)(src + (size_t)r * DM + tx * 4);
        T[tx * 4 + 0][r] = f2bf(v.x); T[tx * 4 + 1][r] = f2bf(v.y);
        T[tx * 4 + 2][r] = f2bf(v.z); T[tx * 4 + 3][r] = f2bf(v.w);
    }
    __syncthreads();
    unsigned short* dst = out + ((size_t)blockIdx.z * DM + c0) * DF + r0;
#pragma unroll
    for (int i = 0; i < 4; ++i) {
        int c = ty + i * 16;
        ushort4 w;
        w.x = T[c][tx * 4 + 0]; w.y = T[c][tx * 4 + 1];
        w.z = T[c][tx * 4 + 2]; w.w = T[c][tx * 4 + 3];
        *(ushort4*)(dst + (size_t)c * DF + tx * 4) = w;
    }
}

// ---------------- GEMM1 (r6-proven): H = gelu(Xb[tok] @ W1), 128x128, BK=32 ---------
__launch_bounds__(256, 3)
__global__ void k_gemm1b(const unsigned short* __restrict__ Xb,
                         const unsigned short* __restrict__ W1T,
                         const int* __restrict__ counts, const int* __restrict__ opad,
                         const int* __restrict__ rowmap, unsigned short* __restrict__ H) {
    const int e = blockIdx.z, mt = blockIdx.y, nt = blockIdx.x;
    const int grow = opad[e] + mt * 128;
    int valid = counts[e] - mt * 128;
    if (valid <= 0) return;
    if (valid > 128) valid = 128;

    __shared__ __align__(16) unsigned short As[128 * 40];
    __shared__ __align__(16) unsigned short Bs[128 * 40];
    __shared__ int toks[128];

    const int tid = threadIdx.x;
    if (tid < 128) {
        int i = (tid < valid) ? tid : 0;
        toks[tid] = rowmap[grow + i] >> 1;
    }
    __syncthreads();

    const int wave = tid >> 6, lane = tid & 63;
    const int wm = wave >> 1, wn = wave & 1;
    const int quad = lane >> 4, l15 = lane & 15;

    f32x4 acc[4][4] = {};

    const int row = tid >> 1, half = tid & 1;
    const unsigned short* ap = Xb + (size_t)toks[row] * DM + half * 16;
    const unsigned short* bp = W1T + ((size_t)e * DF + nt * 128 + row) * DM + half * 16;
    const int lo = row * 40 + half * 16;

    uint4 pa0 = *(const uint4*)ap, pa1 = *(const uint4*)(ap + 8);
    uint4 pb0 = *(const uint4*)bp, pb1 = *(const uint4*)(bp + 8);

    for (int kt = 0; kt < DM / 32; ++kt) {
        *(uint4*)&As[lo] = pa0; *(uint4*)&As[lo + 8] = pa1;
        *(uint4*)&Bs[lo] = pb0; *(uint4*)&Bs[lo + 8] = pb1;
        __syncthreads();
        const int kn = (kt < DM / 32 - 1) ? (kt + 1) * 32 : kt * 32;
        uint4 na0 = *(const uint4*)(ap + kn), na1 = *(const uint4*)(ap + kn + 8);
        uint4 nb0 = *(const uint4*)(bp + kn), nb1 = *(const uint4*)(bp + kn + 8);

        bf16x8 a[4], b[4];
#pragma unroll
        for (int fm = 0; fm < 4; ++fm)
            a[fm] = __builtin_bit_cast(bf16x8, *(const uint4*)&As[(wm * 64 + fm * 16 + l15) * 40 + quad * 8]);
#pragma unroll
        for (int fn = 0; fn < 4; ++fn)
            b[fn] = __builtin_bit_cast(bf16x8, *(const uint4*)&Bs[(wn * 64 + fn * 16 + l15) * 40 + quad * 8]);
#pragma unroll
        for (int fm = 0; fm < 4; ++fm)
#pragma unroll
            for (int fn = 0; fn < 4; ++fn)
                acc[fm][fn] = __builtin_amdgcn_mfma_f32_16x16x32_bf16(a[fm], b[fn], acc[fm][fn], 0, 0, 0);
        __syncthreads();
        pa0 = na0; pa1 = na1; pb0 = nb0; pb1 = nb1;
    }

#pragma unroll
    for (int fm = 0; fm < 4; ++fm) {
#pragma unroll
        for (int i = 0; i < 4; ++i) {
            int m_l = wm * 64 + fm * 16 + quad * 4 + i;
            if (m_l < valid) {
                unsigned short* hrow = H + (size_t)(grow + m_l) * DF + nt * 128 + wn * 64;
#pragma unroll
                for (int fn = 0; fn < 4; ++fn)
                    hrow[fn * 16 + l15] = f2bf(gelu_exact(acc[fm][fn][i]));
            }
        }
    }
}

// ------- GEMM2n: out[pair] = H @ W2, 64x64 tile, full-K (BK=32 x 64), plain stores --
// grid (x=mt, y=nt, z=e): gridDim.x=144 => the 8 nt-siblings sharing one H slice get
// linear ids differing by 144 == 0 (mod 8) -> same XCD -> H slice L2-resident once.
// 4 waves: wave w computes rows 0..63 x cols [w*16, w*16+16). Depth-1 reg prefetch.
__launch_bounds__(256, 4)
__global__ void k_gemm2n(const unsigned short* __restrict__ H,
                         const unsigned short* __restrict__ W2T,
                         const int* __restrict__ counts, const int* __restrict__ opad,
                         const int* __restrict__ rowmap, float* __restrict__ out) {
    const int mt = blockIdx.x, nt = blockIdx.y, e = blockIdx.z;
    const int grow = opad[e] + mt * 64;
    int valid = counts[e] - mt * 64;
    if (valid <= 0) return;
    if (valid > 64) valid = 64;

    __shared__ __align__(16) unsigned short As[64 * 40];
    __shared__ __align__(16) unsigned short Bs[64 * 40];
    __shared__ int pairs[64];

    const int tid = threadIdx.x;
    if (tid < 64) pairs[tid] = (tid < valid) ? rowmap[grow + tid] : 0;

    const int wave = tid >> 6, lane = tid & 63;
    const int quad = lane >> 4, l15 = lane & 15;

    f32x4 acc[4] = {};

    // staging: thread -> (row = tid>>2, sub = tid&3), one 16B chunk of A and of B
    const int row = tid >> 2, sub = tid & 3;
    const int rr = (row < valid) ? row : 0;  // clamp: never read unwritten H
    const unsigned short* ap = H + (size_t)(grow + rr) * DF + sub * 8;
    const unsigned short* bp = W2T + ((size_t)e * DM + nt * 64 + row) * DF + sub * 8;
    const int lo = row * 40 + sub * 8;

    uint4 pa = *(const uint4*)ap, pb = *(const uint4*)bp;

    for (int kt = 0; kt < DF / 32; ++kt) {
        *(uint4*)&As[lo] = pa;
        *(uint4*)&Bs[lo] = pb;
        __syncthreads();
        const int kn = (kt < DF / 32 - 1) ? (kt + 1) * 32 : kt * 32;
        pa = *(const uint4*)(ap + kn);   // prefetch next tile (consumed after 2nd barrier)
        pb = *(const uint4*)(bp + kn);

        bf16x8 b = __builtin_bit_cast(bf16x8,
            *(const uint4*)&Bs[(wave * 16 + l15) * 40 + quad * 8]);
#pragma unroll
        for (int fm = 0; fm < 4; ++fm) {
            bf16x8 a = __builtin_bit_cast(bf16x8,
                *(const uint4*)&As[(fm * 16 + l15) * 40 + quad * 8]);
            acc[fm] = __builtin_amdgcn_mfma_f32_16x16x32_bf16(a, b, acc[fm], 0, 0, 0);
        }
        __syncthreads();
    }

#pragma unroll
    for (int fm = 0; fm < 4; ++fm) {
#pragma unroll
        for (int i = 0; i < 4; ++i) {
            int m_l = fm * 16 + quad * 4 + i;
            if (m_l < valid) {
                float* orow = out + (size_t)pairs[m_l] * DM + nt * 64 + wave * 16;
                orow[l15] = acc[fm][i];
            }
        }
    }
}

extern "C" void kernel_launch(void* const* d_in, const int* in_sizes, int n_in,
                              void* d_out, int out_size, void* d_ws, size_t ws_size,
                              hipStream_t stream) {
    const float* X = (const float*)d_in[0];
    const int* sel = (const int*)d_in[1];
    const float* W1 = (const float*)d_in[3];
    const float* W2 = (const float*)d_in[4];
    float* out = (float*)d_out;
    float* loads_out = out + (size_t)NPAIR * DM;

    int* counts = (int*)d_ws;
    int* opad = counts + 16;
    int* rowmap = counts + 32;
    const size_t hbytes = (size_t)HCAP * DF * 2;
    const size_t xbytes = (size_t)NTOK * DM * 2;
    unsigned short* H = (unsigned short*)((char*)d_ws + 65536);
    unsigned short* Xb = (unsigned short*)((char*)d_ws + 65536 + hbytes);
    unsigned short* WT = (unsigned short*)((char*)d_ws + 65536 + hbytes + xbytes);

    hipLaunchKernelGGL(k_prep, dim3(3073), dim3(256), 0, stream,
                       X, Xb, W1, WT, sel, counts, opad, rowmap, loads_out);
    hipLaunchKernelGGL(k_gemm1b, dim3(DF / 128, NPAIR / 128, NE), dim3(256), 0, stream,
                       Xb, WT, counts, opad, rowmap, H);
    hipLaunchKernelGGL(k_tw2, dim3(DM / 64, DF / 64, NE), dim3(256), 0, stream, W2, WT);
    hipLaunchKernelGGL(k_gemm2n, dim3(HCAP / 64, DM / 64, NE), dim3(256), 0, stream,
                       H, WT, counts, opad, rowmap, out);
}

// Round 9
// 251.646 us; speedup vs baseline: 2.2960x; 1.0086x over previous
//
#include <hip/hip_runtime.h>
#include <hip/hip_bf16.h>

// ExpertBank MoE FFN on gfx950 — round 9.
// 4 dispatches: k_prep(cvtX || tw(W1) || zero(out) || routing) -> GEMM1 -> tw(W2) -> GEMM2.
// GEMMs: m97-style K-loops. Staging via __builtin_amdgcn_global_load_lds width=16
// (4 DMA instr/wave/iter, no VGPR round-trip), unpadded 8KB LDS tiles with XOR slot
// swizzle (frag reads 2-way = free), 4 blocks/CU. gemm2 = split-K x4 + fp32 atomics
// (r4-proven). Fast exp-based GELU (err ~3e-4 << 0.0156 margin).
// ws: int[0..7] counts, [16..23] opad, [32..) rowmap(9216),
//     byte 65536: H bf16 [9216][2048] (37.75 MB), Xb bf16 (4.2 MB),
//     WT bf16 (16.8 MB; W1T then overwritten by W2T). need = 58.85 MB (proven r4/r6/r8).

typedef __bf16 bf16x8 __attribute__((ext_vector_type(8)));
typedef float f32x4 __attribute__((ext_vector_type(4)));

#define DM 512
#define DF 2048
#define NE 8
#define NTOK 4096
#define NPAIR 8192
#define HCAP 9216

__device__ __forceinline__ unsigned short f2bf(float x) {
    unsigned u = __builtin_bit_cast(unsigned, x);
    return (unsigned short)((u + 0x7fffu + ((u >> 16) & 1u)) >> 16);
}
__device__ __forceinline__ unsigned pack2(float lo, float hi) {
    return (unsigned)f2bf(lo) | ((unsigned)f2bf(hi) << 16);
}
__device__ __forceinline__ float gelu_fast(float x) {
    // tanh-form GELU via exp: |err| <= ~3e-4 absolute (h-scale), negligible vs bf16 path
    float y = 0.7978845608028654f * (x + 0.044715f * x * x * x);
    float e = __expf(2.0f * y);
    float t = 1.0f - 2.0f / (e + 1.0f);
    return 0.5f * x * (1.0f + t);
}
// async 16B global->LDS (gfx950); lds pointer must be wave-uniform, writes lane*16B
__device__ __forceinline__ void dma16(const unsigned short* g, unsigned short* l) {
    __builtin_amdgcn_global_load_lds(
        (const __attribute__((address_space(1))) void*)g,
        (__attribute__((address_space(3))) void*)l, 16, 0, 0);
}
// swizzled 16B-slot index for (row, q) in an unpadded [rows][32] bf16 tile
__device__ __forceinline__ int slot_of(int row, int q) {
    return row * 4 + (q ^ ((row >> 1) & 3));
}

// ---- mega-prep: [0,1024) cvtX, [1024,3072) tw(W1), [3072,5120) zero out, 5120 routing ----
__global__ void k_prep(const float* __restrict__ X, unsigned short* __restrict__ Xb,
                       const float* __restrict__ W1, unsigned short* __restrict__ W1T,
                       float* __restrict__ outz,
                       const int* __restrict__ sel, int* __restrict__ counts_g,
                       int* __restrict__ opad_g, int* __restrict__ rowmap,
                       float* __restrict__ loads_out) {
    __shared__ unsigned short T[64][65];
    __shared__ int hist[NE], cur[NE], off[NE];
    const int b = blockIdx.x, tid = threadIdx.x;

    if (b < 1024) {  // X fp32 -> bf16
        int i = (b * 256 + tid) * 8;
        float4 a = *(const float4*)(X + i);
        float4 c = *(const float4*)(X + i + 4);
        uint4 u;
        u.x = pack2(a.x, a.y); u.y = pack2(a.z, a.w);
        u.z = pack2(c.x, c.y); u.w = pack2(c.z, c.w);
        *(uint4*)(Xb + i) = u;
    } else if (b < 3072) {  // W1 [E][DM][DF] -> bf16 W1T [E][DF][DM]
        const int t = b - 1024;
        const int bx = t & 31, by = (t >> 5) & 7, bz = t >> 8;
        const int tx = tid & 15, ty = tid >> 4;
        const int r0 = by * 64, c0 = bx * 64;
        const float* src = W1 + ((size_t)bz * DM + r0) * DF + c0;
#pragma unroll
        for (int i = 0; i < 4; ++i) {
            int r = ty + i * 16;
            float4 v = *(const float4*)(src + (size_t)r * DF + tx * 4);
            T[tx * 4 + 0][r] = f2bf(v.x); T[tx * 4 + 1][r] = f2bf(v.y);
            T[tx * 4 + 2][r] = f2bf(v.z); T[tx * 4 + 3][r] = f2bf(v.w);
        }
        __syncthreads();
        unsigned short* dst = W1T + ((size_t)bz * DF + c0) * DM + r0;
#pragma unroll
        for (int i = 0; i < 4; ++i) {
            int c = ty + i * 16;
            ushort4 w;
            w.x = T[c][tx * 4 + 0]; w.y = T[c][tx * 4 + 1];
            w.z = T[c][tx * 4 + 2]; w.w = T[c][tx * 4 + 3];
            *(ushort4*)(dst + (size_t)c * DM + tx * 4) = w;
        }
    } else if (b < 5120) {  // zero expert_outputs (gemm2 atomics accumulate into it)
        size_t i = ((size_t)(b - 3072) * 256 + tid) * 8;
        float4 z = make_float4(0.f, 0.f, 0.f, 0.f);
        *(float4*)(outz + i) = z;
        *(float4*)(outz + i + 4) = z;
    } else {  // routing: histogram + padded scan + compact assign
        if (tid < NE) { hist[tid] = 0; cur[tid] = 0; }
        __syncthreads();
#pragma unroll
        for (int i = 0; i < NPAIR / 256; ++i)
            atomicAdd(&hist[sel[i * 256 + tid]], 1);
        __syncthreads();
        if (tid == 0) {
            int s = 0;
            for (int e = 0; e < NE; ++e) {
                off[e] = s;
                s += (hist[e] + 127) & ~127;
                counts_g[e] = hist[e];
                opad_g[e] = off[e];
                loads_out[e] = (float)hist[e] * (1.0f / (float)NTOK);
            }
        }
        __syncthreads();
#pragma unroll
        for (int i = 0; i < NPAIR / 256; ++i) {
            int p = i * 256 + tid;
            int e = sel[p];
            int pos = atomicAdd(&cur[e], 1);
            rowmap[off[e] + pos] = p;
        }
    }
}

// ---- W2 [E][DF][DM] -> bf16 W2T [E][DM][DF] ----
__global__ void k_tw2(const float* __restrict__ in, unsigned short* __restrict__ out) {
    __shared__ unsigned short T[64][65];
    const int tid = threadIdx.x;
    const int tx = tid & 15, ty = tid >> 4;
    const int r0 = blockIdx.y * 64, c0 = blockIdx.x * 64;
    const float* src = in + ((size_t)blockIdx.z * DF + r0) * DM + c0;
#pragma unroll
    for (int i = 0; i < 4; ++i) {
        int r = ty + i * 16;
        float4 v = *(const float4*)(src + (size_t)r * DM + tx * 4);
        T[tx * 4 + 0][r] = f2bf(v.x); T[tx * 4 + 1][r] = f2bf(v.y);
        T[tx * 4 + 2][r] = f2bf(v.z); T[tx * 4 + 3][r] = f2bf(v.w);
    }
    __syncthreads();
    unsigned short* dst = out + ((size_t)blockIdx.z * DM + c0) * DF + r0;
#pragma unroll
    for (int i = 0; i < 4; ++i) {
        int c = ty + i * 16;
        ushort4 w;
        w.x = T[c][tx * 4 + 0]; w.y = T[c][tx * 4 + 1];
        w.z = T[c][tx * 4 + 2]; w.w = T[c][tx * 4 + 3];
        *(ushort4*)(dst + (size_t)c * DF + tx * 4) = w;
    }
}

// ---------------- GEMM1: H = gelu(Xb[tok] @ W1), 128x128, BK=32, DMA staging --------
__launch_bounds__(256, 4)
__global__ void k_gemm1d(const unsigned short* __restrict__ Xb,
                         const unsigned short* __restrict__ W1T,
                         const int* __restrict__ counts, const int* __restrict__ opad,
                         const int* __restrict__ rowmap, unsigned short* __restrict__ H) {
    const int e = blockIdx.z, mt = blockIdx.y, nt = blockIdx.x;
    const int grow = opad[e] + mt * 128;
    int valid = counts[e] - mt * 128;
    if (valid <= 0) return;
    if (valid > 128) valid = 128;

    __shared__ __align__(16) unsigned short As[128 * 32];
    __shared__ __align__(16) unsigned short Bs[128 * 32];
    __shared__ int toks[128];

    const int tid = threadIdx.x;
    if (tid < 128) {
        int i = (tid < valid) ? tid : 0;
        toks[tid] = rowmap[grow + i] >> 1;
    }
    __syncthreads();

    const int wave = tid >> 6, lane = tid & 63;
    const int wm = wave >> 1, wn = wave & 1;
    const int quad = lane >> 4, l15 = lane & 15;

    // per-lane DMA source pointers for the 2 A-issues and 2 B-issues of this wave
    const unsigned short* ga[2];
    const unsigned short* gb[2];
    unsigned short* la[2];
    unsigned short* lb[2];
#pragma unroll
    for (int j = 0; j < 2; ++j) {
        int slot = wave * 128 + j * 64 + lane;
        int row = slot >> 2;
        int q = (slot & 3) ^ ((row >> 1) & 3);
        ga[j] = Xb + (size_t)toks[row] * DM + q * 8;
        gb[j] = W1T + ((size_t)e * DF + nt * 128 + row) * DM + q * 8;
        la[j] = &As[(wave * 128 + j * 64) * 8];
        lb[j] = &Bs[(wave * 128 + j * 64) * 8];
    }

    f32x4 acc[4][4] = {};

    for (int kt = 0; kt < DM / 32; ++kt) {
        const int ko = kt * 32;
#pragma unroll
        for (int j = 0; j < 2; ++j) {
            dma16(ga[j] + ko, la[j]);
            dma16(gb[j] + ko, lb[j]);
        }
        __syncthreads();  // drains vmcnt -> LDS tiles complete

        bf16x8 a[4], b[4];
#pragma unroll
        for (int fm = 0; fm < 4; ++fm)
            a[fm] = __builtin_bit_cast(bf16x8, *(const uint4*)&As[slot_of(wm * 64 + fm * 16 + l15, quad) * 8]);
#pragma unroll
        for (int fn = 0; fn < 4; ++fn)
            b[fn] = __builtin_bit_cast(bf16x8, *(const uint4*)&Bs[slot_of(wn * 64 + fn * 16 + l15, quad) * 8]);
#pragma unroll
        for (int fm = 0; fm < 4; ++fm)
#pragma unroll
            for (int fn = 0; fn < 4; ++fn)
                acc[fm][fn] = __builtin_amdgcn_mfma_f32_16x16x32_bf16(a[fm], b[fn], acc[fm][fn], 0, 0, 0);
        __syncthreads();
    }

#pragma unroll
    for (int fm = 0; fm < 4; ++fm) {
#pragma unroll
        for (int i = 0; i < 4; ++i) {
            int m_l = wm * 64 + fm * 16 + quad * 4 + i;
            if (m_l < valid) {
                unsigned short* hrow = H + (size_t)(grow + m_l) * DF + nt * 128 + wn * 64;
#pragma unroll
                for (int fn = 0; fn < 4; ++fn)
                    hrow[fn * 16 + l15] = f2bf(gelu_fast(acc[fm][fn][i]));
            }
        }
    }
}

// ---------------- GEMM2: out += H @ W2, 128x128, split-K x4, DMA staging ------------
__launch_bounds__(256, 4)
__global__ void k_gemm2d(const unsigned short* __restrict__ H,
                         const unsigned short* __restrict__ W2T,
                         const int* __restrict__ counts, const int* __restrict__ opad,
                         const int* __restrict__ rowmap, float* __restrict__ out) {
    const int e = blockIdx.z, mt = blockIdx.y;
    const int nt = blockIdx.x & 3, ks = blockIdx.x >> 2;
    const int grow = opad[e] + mt * 128;
    int valid = counts[e] - mt * 128;
    if (valid <= 0) return;
    if (valid > 128) valid = 128;

    __shared__ __align__(16) unsigned short As[128 * 32];
    __shared__ __align__(16) unsigned short Bs[128 * 32];
    __shared__ int pairs[128];

    const int tid = threadIdx.x;
    if (tid < 128) pairs[tid] = (tid < valid) ? rowmap[grow + tid] : 0;
    __syncthreads();

    const int wave = tid >> 6, lane = tid & 63;
    const int wm = wave >> 1, wn = wave & 1;
    const int quad = lane >> 4, l15 = lane & 15;

    const unsigned short* ga[2];
    const unsigned short* gb[2];
    unsigned short* la[2];
    unsigned short* lb[2];
#pragma unroll
    for (int j = 0; j < 2; ++j) {
        int slot = wave * 128 + j * 64 + lane;
        int row = slot >> 2;
        int q = (slot & 3) ^ ((row >> 1) & 3);
        int rr = (row < valid) ? row : 0;  // clamp: never read unwritten H (r7 lesson)
        ga[j] = H + (size_t)(grow + rr) * DF + ks * 512 + q * 8;
        gb[j] = W2T + ((size_t)e * DM + nt * 128 + row) * DF + ks * 512 + q * 8;
        la[j] = &As[(wave * 128 + j * 64) * 8];
        lb[j] = &Bs[(wave * 128 + j * 64) * 8];
    }

    f32x4 acc[4][4] = {};

    for (int kt = 0; kt < 16; ++kt) {
        const int ko = kt * 32;
#pragma unroll
        for (int j = 0; j < 2; ++j) {
            dma16(ga[j] + ko, la[j]);
            dma16(gb[j] + ko, lb[j]);
        }
        __syncthreads();

        bf16x8 a[4], b[4];
#pragma unroll
        for (int fm = 0; fm < 4; ++fm)
            a[fm] = __builtin_bit_cast(bf16x8, *(const uint4*)&As[slot_of(wm * 64 + fm * 16 + l15, quad) * 8]);
#pragma unroll
        for (int fn = 0; fn < 4; ++fn)
            b[fn] = __builtin_bit_cast(bf16x8, *(const uint4*)&Bs[slot_of(wn * 64 + fn * 16 + l15, quad) * 8]);
#pragma unroll
        for (int fm = 0; fm < 4; ++fm)
#pragma unroll
            for (int fn = 0; fn < 4; ++fn)
                acc[fm][fn] = __builtin_amdgcn_mfma_f32_16x16x32_bf16(a[fm], b[fn], acc[fm][fn], 0, 0, 0);
        __syncthreads();
    }

#pragma unroll
    for (int fm = 0; fm < 4; ++fm) {
#pragma unroll
        for (int i = 0; i < 4; ++i) {
            int m_l = wm * 64 + fm * 16 + quad * 4 + i;
            if (m_l < valid) {
                float* orow = out + (size_t)pairs[m_l] * DM + nt * 128 + wn * 64;
#pragma unroll
                for (int fn = 0; fn < 4; ++fn)
                    atomicAdd(&orow[fn * 16 + l15], acc[fm][fn][i]);
            }
        }
    }
}

extern "C" void kernel_launch(void* const* d_in, const int* in_sizes, int n_in,
                              void* d_out, int out_size, void* d_ws, size_t ws_size,
                              hipStream_t stream) {
    const float* X = (const float*)d_in[0];
    const int* sel = (const int*)d_in[1];
    const float* W1 = (const float*)d_in[3];
    const float* W2 = (const float*)d_in[4];
    float* out = (float*)d_out;
    float* loads_out = out + (size_t)NPAIR * DM;

    int* counts = (int*)d_ws;
    int* opad = counts + 16;
    int* rowmap = counts + 32;
    const size_t hbytes = (size_t)HCAP * DF * 2;
    const size_t xbytes = (size_t)NTOK * DM * 2;
    unsigned short* H = (unsigned short*)((char*)d_ws + 65536);
    unsigned short* Xb = (unsigned short*)((char*)d_ws + 65536 + hbytes);
    unsigned short* WT = (unsigned short*)((char*)d_ws + 65536 + hbytes + xbytes);

    hipLaunchKernelGGL(k_prep, dim3(5121), dim3(256), 0, stream,
                       X, Xb, W1, WT, out, sel, counts, opad, rowmap, loads_out);
    hipLaunchKernelGGL(k_gemm1d, dim3(DF / 128, NPAIR / 128, NE), dim3(256), 0, stream,
                       Xb, WT, counts, opad, rowmap, H);
    hipLaunchKernelGGL(k_tw2, dim3(DM / 64, DF / 64, NE), dim3(256), 0, stream, W2, WT);
    hipLaunchKernelGGL(k_gemm2d, dim3(16, NPAIR / 128, NE), dim3(256), 0, stream,
                       H, WT, counts, opad, rowmap, out);
}